// Round 1
// baseline (162.613 us; speedup 1.0000x reference)
//
#include <hip/hip_runtime.h>
#include <hip/hip_bf16.h>

typedef __attribute__((ext_vector_type(8))) short bf16x8;
typedef __attribute__((ext_vector_type(4))) float f32x4;

#define MFMA16(a, b, c) __builtin_amdgcn_mfma_f32_16x16x32_bf16(a, b, c, 0, 0, 0)

static constexpr int kH = 12;
static constexpr int kN = 1024;
static constexpr int kD = 64;
static constexpr int kTiles = kN / 64;
static constexpr float kScale = 0.125f;
static constexpr float kEps = 1e-6f;

// LDS strides in uints (1 uint = 2 bf16). Rows are 64 bf16 + 8 pad = 72 bf16 = 36 uints.
// Pad keeps 16B alignment for ds_read_b128 and spreads banks (2-way = free).
static constexpr int KSU = 36;
static constexpr int VSU = 36;
static constexpr int PSU = 36;

__device__ __forceinline__ unsigned bfbits(float x) {
    union { __hip_bfloat16 h; unsigned short u; } c;
    c.h = __float2bfloat16(x);
    return (unsigned)c.u;
}
__device__ __forceinline__ unsigned pack2(float a, float b) {
    return bfbits(a) | (bfbits(b) << 16);
}

__global__ __launch_bounds__(256, 3) void l2q_attn(
    const float* __restrict__ q, const float* __restrict__ k, const float* __restrict__ v,
    const float* __restrict__ alpha, const float* __restrict__ beta, const float* __restrict__ gamma,
    float* __restrict__ out)
{
    __shared__ __align__(16) unsigned KsU[64 * KSU];   // K tile  [key][d]   bf16
    __shared__ __align__(16) unsigned VtU[64 * VSU];   // V tile  [d][key]   bf16 (transposed)
    __shared__ __align__(16) unsigned PU[128 * PSU];   // P       [qrow][key] bf16, per-wave 32-row slabs

    const int bid  = blockIdx.x;
    const int bh   = bid >> 3;     // 0..95
    const int qt   = bid & 7;      // q-tile 0..7 (128 rows each)
    const int h    = bh % kH;
    const int t    = threadIdx.x;
    const int wave = t >> 6;
    const int lane = t & 63;
    const int quad = lane >> 4;
    const int l15  = lane & 15;

    const float al = alpha[h], be = beta[h], ga = gamma[h];

    const long base = (long)bh * kN * kD;
    const float* qp = q + base;
    const float* kp = k + base;
    const float* vp = v + base;

    // ---- Q fragments (A-operand: m = l15, k = quad*8+j), loaded once ----
    bf16x8 qa[2][2];
#pragma unroll
    for (int rb = 0; rb < 2; ++rb) {
        const int row = qt * 128 + wave * 32 + rb * 16 + l15;
#pragma unroll
        for (int kc = 0; kc < 2; ++kc) {
            const float* src = qp + (long)row * kD + kc * 32 + quad * 8;
            const float4 f0 = *(const float4*)(src);
            const float4 f1 = *(const float4*)(src + 4);
            bf16x8 a;
            a[0] = (short)bfbits(f0.x); a[1] = (short)bfbits(f0.y);
            a[2] = (short)bfbits(f0.z); a[3] = (short)bfbits(f0.w);
            a[4] = (short)bfbits(f1.x); a[5] = (short)bfbits(f1.y);
            a[6] = (short)bfbits(f1.z); a[7] = (short)bfbits(f1.w);
            qa[rb][kc] = a;
        }
    }

    f32x4 oacc[2][4];
#pragma unroll
    for (int rb = 0; rb < 2; ++rb)
#pragma unroll
        for (int db = 0; db < 4; ++db)
            oacc[rb][db] = (f32x4){0.f, 0.f, 0.f, 0.f};

    float dsum[2][4] = {{0.f, 0.f, 0.f, 0.f}, {0.f, 0.f, 0.f, 0.f}};

    unsigned* Pw = &PU[wave * 32 * PSU];

    for (int tile = 0; tile < kTiles; ++tile) {
        __syncthreads();   // all waves done reading previous K/V tiles
        const int k0 = tile * 64;

        // ---- stage K tile: global fp32 [key][d] -> LDS bf16 [key][d] ----
#pragma unroll
        for (int r = 0; r < 4; ++r) {
            const int f4 = t + 256 * r;          // 1024 float4s = 64 rows x 16
            const int n = f4 >> 4, d4 = f4 & 15;
            const float4 kg = *(const float4*)(kp + (long)(k0 + n) * kD + 4 * d4);
            uint2 pk;
            pk.x = pack2(kg.x, kg.y);
            pk.y = pack2(kg.z, kg.w);
            *(uint2*)&KsU[n * KSU + 2 * d4] = pk;
        }
        // ---- stage V tile transposed: global fp32 [key][d] -> LDS bf16 [d][key] ----
        // unit = 2 adjacent keys x 4 d's -> b32 stores of key-pairs, conflict-free banks
#pragma unroll
        for (int r = 0; r < 2; ++r) {
            const int u = t + 256 * r;           // 512 units
            const int key2 = u & 31, d4 = u >> 5;
            const float* s0 = vp + (long)(k0 + 2 * key2) * kD + 4 * d4;
            const float4 va = *(const float4*)(s0);
            const float4 vb = *(const float4*)(s0 + kD);
            VtU[(4 * d4 + 0) * VSU + key2] = pack2(va.x, vb.x);
            VtU[(4 * d4 + 1) * VSU + key2] = pack2(va.y, vb.y);
            VtU[(4 * d4 + 2) * VSU + key2] = pack2(va.z, vb.z);
            VtU[(4 * d4 + 3) * VSU + key2] = pack2(va.w, vb.w);
        }
        __syncthreads();

        // ---- S = Q K^T  (16x16 blocks; rb = q-rowblock, nb = key-colblock) ----
        f32x4 s[2][4];
#pragma unroll
        for (int rb = 0; rb < 2; ++rb)
#pragma unroll
            for (int nb = 0; nb < 4; ++nb)
                s[rb][nb] = (f32x4){0.f, 0.f, 0.f, 0.f};
#pragma unroll
        for (int nb = 0; nb < 4; ++nb) {
            bf16x8 kb0 = *(const bf16x8*)&KsU[(nb * 16 + l15) * KSU + 4 * quad];
            bf16x8 kb1 = *(const bf16x8*)&KsU[(nb * 16 + l15) * KSU + 16 + 4 * quad];
#pragma unroll
            for (int rb = 0; rb < 2; ++rb) {
                s[rb][nb] = MFMA16(qa[rb][0], kb0, s[rb][nb]);
                s[rb][nb] = MFMA16(qa[rb][1], kb1, s[rb][nb]);
            }
        }

        // ---- poly + relu; denominator partials; pack P to LDS (bf16) ----
        const bool ev = (lane & 1) == 0;
#pragma unroll
        for (int rb = 0; rb < 2; ++rb) {
#pragma unroll
            for (int nb = 0; nb < 4; ++nb) {
                float w0, w1, w2, w3;
                {
                    float l0 = s[rb][nb][0] * kScale;
                    float l1 = s[rb][nb][1] * kScale;
                    float l2 = s[rb][nb][2] * kScale;
                    float l3 = s[rb][nb][3] * kScale;
                    w0 = fmaxf(fmaf(fmaf(al, l0, be), l0, ga), 0.f);
                    w1 = fmaxf(fmaf(fmaf(al, l1, be), l1, ga), 0.f);
                    w2 = fmaxf(fmaf(fmaf(al, l2, be), l2, ga), 0.f);
                    w3 = fmaxf(fmaf(fmaf(al, l3, be), l3, ga), 0.f);
                }
                dsum[rb][0] += w0; dsum[rb][1] += w1;
                dsum[rb][2] += w2; dsum[rb][3] += w3;

                // lane-pair packing: even lane writes rows quad*4+{0,1}, odd rows quad*4+{2,3}
                const float o0 = __shfl_xor(w0, 1);
                const float o1 = __shfl_xor(w1, 1);
                const float o2 = __shfl_xor(w2, 1);
                const float o3 = __shfl_xor(w3, 1);
                const unsigned pa = ev ? pack2(w0, o0) : pack2(o2, w2);
                const unsigned pb = ev ? pack2(w1, o1) : pack2(o3, w3);
                const int r0 = ev ? 0 : 2;
                const int cu = (16 * nb + (l15 & ~1)) >> 1;   // uint column
                const int rowb = rb * 16 + quad * 4 + r0;
                Pw[rowb * PSU + cu] = pa;
                Pw[(rowb + 1) * PSU + cu] = pb;
            }
        }
        // Within-wave write->read: compiler inserts lgkmcnt waits; no __syncthreads needed
        // (each wave reads only its own 32-row P slab).

        // ---- O += P V  (A = P, B = V^T-layout) ----
        bf16x8 pf[2][2];
#pragma unroll
        for (int rb = 0; rb < 2; ++rb)
#pragma unroll
            for (int kc = 0; kc < 2; ++kc)
                pf[rb][kc] = *(const bf16x8*)&Pw[(rb * 16 + l15) * PSU + 16 * kc + 4 * quad];
#pragma unroll
        for (int db = 0; db < 4; ++db) {
            bf16x8 vf0 = *(const bf16x8*)&VtU[(db * 16 + l15) * VSU + 4 * quad];
            bf16x8 vf1 = *(const bf16x8*)&VtU[(db * 16 + l15) * VSU + 16 + 4 * quad];
#pragma unroll
            for (int rb = 0; rb < 2; ++rb) {
                oacc[rb][db] = MFMA16(pf[rb][0], vf0, oacc[rb][db]);
                oacc[rb][db] = MFMA16(pf[rb][1], vf1, oacc[rb][db]);
            }
        }
    }

    // ---- denominator: reduce across the 16 lanes of each quad (C-layout rows) ----
#pragma unroll
    for (int rb = 0; rb < 2; ++rb)
#pragma unroll
        for (int i = 0; i < 4; ++i) {
            float d = dsum[rb][i];
            d += __shfl_xor(d, 1);
            d += __shfl_xor(d, 2);
            d += __shfl_xor(d, 4);
            d += __shfl_xor(d, 8);
            dsum[rb][i] = 1.0f / (d + kEps);
        }

    // ---- write output: C-layout row = quad*4+i, col = db*16 + l15 ----
#pragma unroll
    for (int rb = 0; rb < 2; ++rb)
#pragma unroll
        for (int db = 0; db < 4; ++db)
#pragma unroll
            for (int i = 0; i < 4; ++i) {
                const int row = qt * 128 + wave * 32 + rb * 16 + quad * 4 + i;
                out[base + (long)row * kD + db * 16 + l15] = oacc[rb][db][i] * dsum[rb][i];
            }
}

extern "C" void kernel_launch(void* const* d_in, const int* in_sizes, int n_in,
                              void* d_out, int out_size, void* d_ws, size_t ws_size,
                              hipStream_t stream) {
    const float* q     = (const float*)d_in[0];
    const float* k     = (const float*)d_in[1];
    const float* v     = (const float*)d_in[2];
    const float* alpha = (const float*)d_in[3];
    const float* beta  = (const float*)d_in[4];
    const float* gamma = (const float*)d_in[5];
    float* out = (float*)d_out;

    l2q_attn<<<dim3(768), dim3(256), 0, stream>>>(q, k, v, alpha, beta, gamma, out);
}

// Round 2
// 158.455 us; speedup vs baseline: 1.0262x; 1.0262x over previous
//
#include <hip/hip_runtime.h>
#include <hip/hip_bf16.h>

typedef __attribute__((ext_vector_type(8))) short bf16x8;
typedef __attribute__((ext_vector_type(4))) float f32x4;

#define MFMA16(a, b, c) __builtin_amdgcn_mfma_f32_16x16x32_bf16(a, b, c, 0, 0, 0)

static constexpr int kH = 12;
static constexpr int kN = 1024;
static constexpr int kD = 64;
static constexpr int kBH = 96;                 // B*H
static constexpr int kND = kN * kD;            // 65536 elems per head
static constexpr int kTiles = kN / 64;
static constexpr float kScale = 0.125f;
static constexpr float kEps = 1e-6f;
static constexpr long kTensorElems = (long)kBH * kND;          // 6291456
static constexpr long kWsNeeded = 3 * kTensorElems * 2;        // 37748736 bytes

// ---------- bf16 helpers ----------
__device__ __forceinline__ unsigned bfbits(float x) {
    union { __hip_bfloat16 h; unsigned short u; } c;
    c.h = __float2bfloat16(x);
    return (unsigned)c.u;
}
__device__ __forceinline__ unsigned pack2_rne(float a, float b) {
    return bfbits(a) | (bfbits(b) << 16);
}
// round-half-up pack (P >= 0 post-ReLU): 2 adds + 1 v_perm
__device__ __forceinline__ unsigned pack2_rhu(float lo, float hi) {
    unsigned a = __builtin_bit_cast(unsigned, lo) + 0x8000u;
    unsigned b = __builtin_bit_cast(unsigned, hi) + 0x8000u;
    return __builtin_amdgcn_perm(b, a, 0x07060302u);   // {b.hi16 | a.hi16<<16}? -> low16=a.hi, high16=b.hi
}

__device__ __forceinline__ void gl_lds16(const void* g, void* l) {
    __builtin_amdgcn_global_load_lds(
        (const __attribute__((address_space(1))) void*)g,
        (__attribute__((address_space(3))) void*)l, 16, 0, 0);
}

// ---------- pre-pass 1: cast Q,K fp32 -> bf16 ----------
__global__ __launch_bounds__(256, 4) void cast_qk(
    const float* __restrict__ q, const float* __restrict__ k,
    unsigned* __restrict__ qo, unsigned* __restrict__ ko)
{
    const int tid = blockIdx.x * 256 + threadIdx.x;       // grid 1536*256 = 393216
    const int stride = 1536 * 256;
    const long perT = kTensorElems / 4;                   // 1572864 float4 per tensor
#pragma unroll
    for (int r = 0; r < 8; ++r) {
        long i = (long)tid + (long)r * stride;            // 0 .. 3145727
        const float4* src; unsigned* dst; long j;
        if (i < perT) { src = (const float4*)q; dst = qo; j = i; }
        else          { src = (const float4*)k; dst = ko; j = i - perT; }
        float4 f = src[j];
        uint2 u;
        u.x = pack2_rne(f.x, f.y);
        u.y = pack2_rne(f.z, f.w);
        *(uint2*)&dst[j * 2] = u;
    }
}

// ---------- pre-pass 2: V [bh][n][d] fp32 -> Vt [bh][d][n] bf16 ----------
__global__ __launch_bounds__(256, 4) void vtrans(
    const float* __restrict__ v, unsigned* __restrict__ vt)
{
    static constexpr int TS = 68;                         // fp32 stride (16B-aligned rows)
    __shared__ float T32[64 * TS];
    const int bid = blockIdx.x;                           // 1536 = 96 bh * 16 kt
    const int bh = bid >> 4, kt = bid & 15;
    const int t = threadIdx.x;
    const float* vp = v + (long)bh * kND + (long)kt * 64 * kD;

#pragma unroll
    for (int r = 0; r < 4; ++r) {
        const int f4 = t + 256 * r;                       // 1024 float4 = 64 rows x 16
        const int n = f4 >> 4, d4 = f4 & 15;
        const float4 f = *(const float4*)(vp + (long)n * kD + 4 * d4);
        *(float4*)&T32[n * TS + 4 * d4] = f;
    }
    __syncthreads();

    const int d = t >> 2, c = t & 3;                      // d row, 16-key chunk
    unsigned u[8];
#pragma unroll
    for (int j = 0; j < 8; ++j) {
        const int key = c * 16 + 2 * j;
        u[j] = pack2_rne(T32[key * TS + d], T32[(key + 1) * TS + d]);
    }
    unsigned* dst = vt + (long)bh * (kND / 2) + (long)d * (kN / 2) + kt * 32 + c * 8;
    *(uint4*)(dst)     = *(uint4*)&u[0];
    *(uint4*)(dst + 4) = *(uint4*)&u[4];
}

// ---------- main attention kernel (bf16 inputs from ws) ----------
__global__ __launch_bounds__(256, 3) void l2q_main(
    const unsigned short* __restrict__ qbf, const unsigned short* __restrict__ kbf,
    const unsigned short* __restrict__ vtbf,
    const float* __restrict__ alpha, const float* __restrict__ beta, const float* __restrict__ gamma,
    float* __restrict__ out)
{
    // K/V tiles: 64 rows x 64 bf16 = 128B rows = 8 granules(16B); XOR-swizzled, no pad.
    __shared__ __align__(16) unsigned Ks[2][2048];
    __shared__ __align__(16) unsigned Vs[2][2048];
    __shared__ __align__(16) unsigned Pu[4][1024];   // per-wave 32 qrows x 64 keys bf16

    const int bid  = blockIdx.x;
    const int bh   = bid >> 3;
    const int qt   = bid & 7;
    const int h    = bh % kH;
    const int t    = threadIdx.x;
    const int wave = t >> 6;
    const int lane = t & 63;
    const int quad = lane >> 4;
    const int l15  = lane & 15;
    const int sw   = l15 & 7;

    const float al = alpha[h] * (kScale * kScale);
    const float be = beta[h] * kScale;
    const float ga = gamma[h];

    const unsigned short* qp = qbf + (long)bh * kND;
    const unsigned short* kp = kbf + (long)bh * kND;
    const unsigned short* vp = vtbf + (long)bh * kND;   // [d][n] layout

    // Q fragments: lane holds Q[q = qb*16+l15][d = kc*32 + quad*8 + j]
    bf16x8 qa[2][2];
#pragma unroll
    for (int qb = 0; qb < 2; ++qb) {
        const int row = qt * 128 + wave * 32 + qb * 16 + l15;
#pragma unroll
        for (int kc = 0; kc < 2; ++kc)
            qa[qb][kc] = *(const bf16x8*)(qp + (long)row * kD + kc * 32 + quad * 8);
    }

    f32x4 oacc[2][4];
#pragma unroll
    for (int qb = 0; qb < 2; ++qb)
#pragma unroll
        for (int db = 0; db < 4; ++db)
            oacc[qb][db] = (f32x4){0.f, 0.f, 0.f, 0.f};
    f32x4 dsv[2] = {(f32x4){0.f,0.f,0.f,0.f}, (f32x4){0.f,0.f,0.f,0.f}};

    // staging geometry: per call a wave fills 1KB (8 rows); 2 calls = block covers 64 rows
    const int srow = lane >> 3;          // row-in-segment 0..7
    const int g    = lane & 7;           // phys granule slot
    auto stageKV = [&](int buf, int tile) {
        const int k0 = tile * 64;
#pragma unroll
        for (int c = 0; c < 2; ++c) {
            const int r  = (c * 4 + wave) * 8 + srow;          // 0..63
            const int gl = (g ^ (r & 7)) * 8;                  // swizzled chunk (bf16 units)
            gl_lds16(kp + (long)(k0 + r) * kD + gl, &Ks[buf][(c * 4 + wave) * 256]);
            gl_lds16(vp + (long)r * kN + k0 + gl,   &Vs[buf][(c * 4 + wave) * 256]);
        }
    };

    stageKV(0, 0);

    unsigned* Pw = Pu[wave];

    for (int tile = 0; tile < kTiles; ++tile) {
        const int buf = tile & 1;
        __syncthreads();                       // drains vmcnt: tile's loads done; prev buf readers done
        if (tile + 1 < kTiles) stageKV(buf ^ 1, tile + 1);

        const unsigned* Kb = Ks[buf];
        const unsigned* Vb = Vs[buf];

        // ---- S^T = K Q^T : C[m=key][n=q]; lane holds 4 keys (quad*4+i), qrow=l15 ----
        f32x4 st[2][4];
#pragma unroll
        for (int qb = 0; qb < 2; ++qb)
#pragma unroll
            for (int kb = 0; kb < 4; ++kb)
                st[qb][kb] = (f32x4){0.f, 0.f, 0.f, 0.f};
#pragma unroll
        for (int kb = 0; kb < 4; ++kb) {
            const int row = kb * 16 + l15;
            bf16x8 kf0 = *(const bf16x8*)&Kb[row * 32 + ((quad ^ sw) << 2)];
            bf16x8 kf1 = *(const bf16x8*)&Kb[row * 32 + (((4 + quad) ^ sw) << 2)];
#pragma unroll
            for (int qb = 0; qb < 2; ++qb) {
                st[qb][kb] = MFMA16(kf0, qa[qb][0], st[qb][kb]);
                st[qb][kb] = MFMA16(kf1, qa[qb][1], st[qb][kb]);
            }
        }

        // ---- poly + ReLU + denom + pack P (bf16, in-lane pairs, no shfl) ----
#pragma unroll
        for (int qb = 0; qb < 2; ++qb) {
            const int pbase = (qb * 16 + l15) * 32;
#pragma unroll
            for (int kb = 0; kb < 4; ++kb) {
                f32x4 s = st[qb][kb];
                f32x4 w = s * al + be;
                w = w * s + ga;
                w[0] = fmaxf(w[0], 0.f); w[1] = fmaxf(w[1], 0.f);
                w[2] = fmaxf(w[2], 0.f); w[3] = fmaxf(w[3], 0.f);
                dsv[qb] += w;
                uint2 pk2;
                pk2.x = pack2_rhu(w[0], w[1]);
                pk2.y = pack2_rhu(w[2], w[3]);
                const int col = kb * 8 + quad * 2;              // uint col (keys quad*4..)
                const int gr = col >> 2, off = col & 3;
                *(uint2*)&Pw[pbase + ((gr ^ sw) << 2) + off] = pk2;
            }
        }

        // ---- O += P V : A=P[q][key], B=V[key][d] from Vt LDS ----
        bf16x8 pf[2][2];
#pragma unroll
        for (int qb = 0; qb < 2; ++qb) {
            const int pbase = (qb * 16 + l15) * 32;
            pf[qb][0] = *(const bf16x8*)&Pw[pbase + ((quad ^ sw) << 2)];
            pf[qb][1] = *(const bf16x8*)&Pw[pbase + (((4 + quad) ^ sw) << 2)];
        }
#pragma unroll
        for (int db = 0; db < 4; ++db) {
            const int vrow = db * 16 + l15;
            bf16x8 vf0 = *(const bf16x8*)&Vb[vrow * 32 + ((quad ^ sw) << 2)];
            bf16x8 vf1 = *(const bf16x8*)&Vb[vrow * 32 + (((4 + quad) ^ sw) << 2)];
#pragma unroll
            for (int qb = 0; qb < 2; ++qb) {
                oacc[qb][db] = MFMA16(pf[qb][0], vf0, oacc[qb][db]);
                oacc[qb][db] = MFMA16(pf[qb][1], vf1, oacc[qb][db]);
            }
        }
    }

    // ---- denominator: horizontal + cross-quad; then gather per output row ----
    float dr[2];
#pragma unroll
    for (int qb = 0; qb < 2; ++qb) {
        float d = dsv[qb][0] + dsv[qb][1] + dsv[qb][2] + dsv[qb][3];
        d += __shfl_xor(d, 16);
        d += __shfl_xor(d, 32);
        dr[qb] = 1.0f / (d + kEps);
    }

    const long obase = (long)bh * kND;
#pragma unroll
    for (int qb = 0; qb < 2; ++qb)
#pragma unroll
        for (int i = 0; i < 4; ++i) {
            const float rr = __shfl(dr[qb], quad * 4 + i);
            const int row = qt * 128 + wave * 32 + qb * 16 + quad * 4 + i;
#pragma unroll
            for (int db = 0; db < 4; ++db)
                out[obase + (long)row * kD + db * 16 + l15] = oacc[qb][db][i] * rr;
        }
}

// ---------- fallback (R1 kernel, fp32 direct) for small ws ----------
static constexpr int KSU = 36;
static constexpr int VSU = 36;
static constexpr int PSU = 36;

__global__ __launch_bounds__(256, 3) void l2q_attn_fb(
    const float* __restrict__ q, const float* __restrict__ k, const float* __restrict__ v,
    const float* __restrict__ alpha, const float* __restrict__ beta, const float* __restrict__ gamma,
    float* __restrict__ out)
{
    __shared__ __align__(16) unsigned KsU[64 * KSU];
    __shared__ __align__(16) unsigned VtU[64 * VSU];
    __shared__ __align__(16) unsigned PU[128 * PSU];

    const int bid  = blockIdx.x;
    const int bh   = bid >> 3;
    const int qt   = bid & 7;
    const int h    = bh % kH;
    const int t    = threadIdx.x;
    const int wave = t >> 6;
    const int lane = t & 63;
    const int quad = lane >> 4;
    const int l15  = lane & 15;

    const float al = alpha[h], be = beta[h], ga = gamma[h];

    const long base = (long)bh * kN * kD;
    const float* qp = q + base;
    const float* kp = k + base;
    const float* vp = v + base;

    bf16x8 qa[2][2];
#pragma unroll
    for (int rb = 0; rb < 2; ++rb) {
        const int row = qt * 128 + wave * 32 + rb * 16 + l15;
#pragma unroll
        for (int kc = 0; kc < 2; ++kc) {
            const float* src = qp + (long)row * kD + kc * 32 + quad * 8;
            const float4 f0 = *(const float4*)(src);
            const float4 f1 = *(const float4*)(src + 4);
            bf16x8 a;
            a[0] = (short)bfbits(f0.x); a[1] = (short)bfbits(f0.y);
            a[2] = (short)bfbits(f0.z); a[3] = (short)bfbits(f0.w);
            a[4] = (short)bfbits(f1.x); a[5] = (short)bfbits(f1.y);
            a[6] = (short)bfbits(f1.z); a[7] = (short)bfbits(f1.w);
            qa[rb][kc] = a;
        }
    }

    f32x4 oacc[2][4];
#pragma unroll
    for (int rb = 0; rb < 2; ++rb)
#pragma unroll
        for (int db = 0; db < 4; ++db)
            oacc[rb][db] = (f32x4){0.f, 0.f, 0.f, 0.f};

    float dsum[2][4] = {{0.f, 0.f, 0.f, 0.f}, {0.f, 0.f, 0.f, 0.f}};
    unsigned* Pw = &PU[wave * 32 * PSU];

    for (int tile = 0; tile < kTiles; ++tile) {
        __syncthreads();
        const int k0 = tile * 64;
#pragma unroll
        for (int r = 0; r < 4; ++r) {
            const int f4 = t + 256 * r;
            const int n = f4 >> 4, d4 = f4 & 15;
            const float4 kg = *(const float4*)(kp + (long)(k0 + n) * kD + 4 * d4);
            uint2 pk;
            pk.x = pack2_rne(kg.x, kg.y);
            pk.y = pack2_rne(kg.z, kg.w);
            *(uint2*)&KsU[n * KSU + 2 * d4] = pk;
        }
#pragma unroll
        for (int r = 0; r < 2; ++r) {
            const int u = t + 256 * r;
            const int key2 = u & 31, d4 = u >> 5;
            const float* s0 = vp + (long)(k0 + 2 * key2) * kD + 4 * d4;
            const float4 va = *(const float4*)(s0);
            const float4 vb = *(const float4*)(s0 + kD);
            VtU[(4 * d4 + 0) * VSU + key2] = pack2_rne(va.x, vb.x);
            VtU[(4 * d4 + 1) * VSU + key2] = pack2_rne(va.y, vb.y);
            VtU[(4 * d4 + 2) * VSU + key2] = pack2_rne(va.z, vb.z);
            VtU[(4 * d4 + 3) * VSU + key2] = pack2_rne(va.w, vb.w);
        }
        __syncthreads();

        f32x4 s[2][4];
#pragma unroll
        for (int rb = 0; rb < 2; ++rb)
#pragma unroll
            for (int nb = 0; nb < 4; ++nb)
                s[rb][nb] = (f32x4){0.f, 0.f, 0.f, 0.f};
#pragma unroll
        for (int nb = 0; nb < 4; ++nb) {
            bf16x8 kb0 = *(const bf16x8*)&KsU[(nb * 16 + l15) * KSU + 4 * quad];
            bf16x8 kb1 = *(const bf16x8*)&KsU[(nb * 16 + l15) * KSU + 16 + 4 * quad];
#pragma unroll
            for (int rb = 0; rb < 2; ++rb) {
                s[rb][nb] = MFMA16(qa[rb][0], kb0, s[rb][nb]);
                s[rb][nb] = MFMA16(qa[rb][1], kb1, s[rb][nb]);
            }
        }

        const bool ev = (lane & 1) == 0;
#pragma unroll
        for (int rb = 0; rb < 2; ++rb) {
#pragma unroll
            for (int nb = 0; nb < 4; ++nb) {
                float w0, w1, w2, w3;
                {
                    float l0 = s[rb][nb][0] * kScale;
                    float l1 = s[rb][nb][1] * kScale;
                    float l2 = s[rb][nb][2] * kScale;
                    float l3 = s[rb][nb][3] * kScale;
                    w0 = fmaxf(fmaf(fmaf(al, l0, be), l0, ga), 0.f);
                    w1 = fmaxf(fmaf(fmaf(al, l1, be), l1, ga), 0.f);
                    w2 = fmaxf(fmaf(fmaf(al, l2, be), l2, ga), 0.f);
                    w3 = fmaxf(fmaf(fmaf(al, l3, be), l3, ga), 0.f);
                }
                dsum[rb][0] += w0; dsum[rb][1] += w1;
                dsum[rb][2] += w2; dsum[rb][3] += w3;

                const float o0 = __shfl_xor(w0, 1);
                const float o1 = __shfl_xor(w1, 1);
                const float o2 = __shfl_xor(w2, 1);
                const float o3 = __shfl_xor(w3, 1);
                const unsigned pa = ev ? pack2_rne(w0, o0) : pack2_rne(o2, w2);
                const unsigned pb = ev ? pack2_rne(w1, o1) : pack2_rne(o3, w3);
                const int r0 = ev ? 0 : 2;
                const int cu = (16 * nb + (l15 & ~1)) >> 1;
                const int rowb = rb * 16 + quad * 4 + r0;
                Pw[rowb * PSU + cu] = pa;
                Pw[(rowb + 1) * PSU + cu] = pb;
            }
        }

        bf16x8 pf[2][2];
#pragma unroll
        for (int rb = 0; rb < 2; ++rb)
#pragma unroll
            for (int kc = 0; kc < 2; ++kc)
                pf[rb][kc] = *(const bf16x8*)&Pw[(rb * 16 + l15) * PSU + 16 * kc + 4 * quad];
#pragma unroll
        for (int db = 0; db < 4; ++db) {
            bf16x8 vf0 = *(const bf16x8*)&VtU[(db * 16 + l15) * VSU + 4 * quad];
            bf16x8 vf1 = *(const bf16x8*)&VtU[(db * 16 + l15) * VSU + 16 + 4 * quad];
#pragma unroll
            for (int rb = 0; rb < 2; ++rb) {
                oacc[rb][db] = MFMA16(pf[rb][0], vf0, oacc[rb][db]);
                oacc[rb][db] = MFMA16(pf[rb][1], vf1, oacc[rb][db]);
            }
        }
    }

#pragma unroll
    for (int rb = 0; rb < 2; ++rb)
#pragma unroll
        for (int i = 0; i < 4; ++i) {
            float d = dsum[rb][i];
            d += __shfl_xor(d, 1);
            d += __shfl_xor(d, 2);
            d += __shfl_xor(d, 4);
            d += __shfl_xor(d, 8);
            dsum[rb][i] = 1.0f / (d + kEps);
        }

#pragma unroll
    for (int rb = 0; rb < 2; ++rb)
#pragma unroll
        for (int db = 0; db < 4; ++db)
#pragma unroll
            for (int i = 0; i < 4; ++i) {
                const int row = qt * 128 + wave * 32 + rb * 16 + quad * 4 + i;
                out[base + (long)row * kD + db * 16 + l15] = oacc[rb][db][i] * dsum[rb][i];
            }
}

extern "C" void kernel_launch(void* const* d_in, const int* in_sizes, int n_in,
                              void* d_out, int out_size, void* d_ws, size_t ws_size,
                              hipStream_t stream) {
    const float* q     = (const float*)d_in[0];
    const float* k     = (const float*)d_in[1];
    const float* v     = (const float*)d_in[2];
    const float* alpha = (const float*)d_in[3];
    const float* beta  = (const float*)d_in[4];
    const float* gamma = (const float*)d_in[5];
    float* out = (float*)d_out;

    if (ws_size < (size_t)kWsNeeded) {
        l2q_attn_fb<<<dim3(768), dim3(256), 0, stream>>>(q, k, v, alpha, beta, gamma, out);
        return;
    }

    unsigned* qbf = (unsigned*)d_ws;                          // as uint pairs
    unsigned* kbf = qbf + kTensorElems / 2;
    unsigned* vtb = kbf + kTensorElems / 2;

    cast_qk<<<dim3(1536), dim3(256), 0, stream>>>(q, k, qbf, kbf);
    vtrans<<<dim3(1536), dim3(256), 0, stream>>>(v, vtb);
    l2q_main<<<dim3(768), dim3(256), 0, stream>>>(
        (const unsigned short*)qbf, (const unsigned short*)kbf, (const unsigned short*)vtb,
        alpha, beta, gamma, out);
}

// Round 3
// 157.921 us; speedup vs baseline: 1.0297x; 1.0034x over previous
//
#include <hip/hip_runtime.h>
#include <hip/hip_bf16.h>

typedef __attribute__((ext_vector_type(8))) short bf16x8;
typedef __attribute__((ext_vector_type(4))) float f32x4;

#define MFMA16(a, b, c) __builtin_amdgcn_mfma_f32_16x16x32_bf16(a, b, c, 0, 0, 0)

static constexpr int kH = 12;
static constexpr int kN = 1024;
static constexpr int kD = 64;
static constexpr int kBH = 96;
static constexpr int kND = kN * kD;            // 65536 per head
static constexpr int kTiles = kN / 32;         // 32-key tiles
static constexpr float kScale = 0.125f;
static constexpr float kEps = 1e-6f;
static constexpr long kTensorElems = (long)kBH * kND;     // 6291456
static constexpr long kWsNeeded = 2 * kTensorElems * 2;   // K + Vt bf16 = 25165824 B

// ---------- bf16 helpers ----------
__device__ __forceinline__ unsigned bfbits(float x) {
    union { __hip_bfloat16 h; unsigned short u; } c;
    c.h = __float2bfloat16(x);
    return (unsigned)c.u;
}
__device__ __forceinline__ unsigned pack2_rne(float a, float b) {
    return bfbits(a) | (bfbits(b) << 16);
}
// round-half-up pack (P >= 0 post-ReLU): 2 adds + 1 v_perm
__device__ __forceinline__ unsigned pack2_rhu(float lo, float hi) {
    unsigned a = __builtin_bit_cast(unsigned, lo) + 0x8000u;
    unsigned b = __builtin_bit_cast(unsigned, hi) + 0x8000u;
    return __builtin_amdgcn_perm(b, a, 0x07060302u);
}
__device__ __forceinline__ void gl_lds16(const void* g, void* l) {
    __builtin_amdgcn_global_load_lds(
        (const __attribute__((address_space(1))) void*)g,
        (__attribute__((address_space(3))) void*)l, 16, 0, 0);
}

// ---------- prepass: K fp32->bf16 cast + V fp32 [n][d] -> Vt bf16 [d][n] ----------
__global__ __launch_bounds__(256, 2) void prep(
    const float* __restrict__ k, const float* __restrict__ v,
    unsigned* __restrict__ kbf, unsigned* __restrict__ vtb)
{
    static constexpr int TS = 68;                 // fp32 LDS row stride
    __shared__ float T32[64 * TS];
    const int bid = blockIdx.x;                   // 1536 = 96 bh * 16 nt
    const int bh = bid >> 4, nt = bid & 15;
    const int t = threadIdx.x;

    // --- K cast: 64 rows x 64 d, layout preserved ---
    const float* kp = k + (long)bh * kND + (long)nt * 64 * kD;
    unsigned* ko = kbf + ((long)bh * kND + (long)nt * 64 * kD) / 2;
#pragma unroll
    for (int r = 0; r < 4; ++r) {
        const int f4 = t + 256 * r;               // 1024 float4
        const float4 f = ((const float4*)kp)[f4];
        uint2 u;
        u.x = pack2_rne(f.x, f.y);
        u.y = pack2_rne(f.z, f.w);
        *(uint2*)&ko[f4 * 2] = u;
    }

    // --- V transpose: tile rows nt*64..+63 -> Vt[d][n] ---
    const float* vp = v + (long)bh * kND + (long)nt * 64 * kD;
#pragma unroll
    for (int r = 0; r < 4; ++r) {
        const int f4 = t + 256 * r;
        const int n = f4 >> 4, d4 = f4 & 15;
        const float4 f = *(const float4*)(vp + (long)n * kD + 4 * d4);
        *(float4*)&T32[n * TS + 4 * d4] = f;
    }
    __syncthreads();
    const int d = t >> 2, c = t & 3;              // d row, 16-key chunk
    unsigned u[8];
#pragma unroll
    for (int j = 0; j < 8; ++j) {
        const int key = c * 16 + 2 * j;
        u[j] = pack2_rne(T32[key * TS + d], T32[(key + 1) * TS + d]);
    }
    unsigned* dst = vtb + (long)bh * (kND / 2) + (long)d * (kN / 2) + nt * 32 + c * 8;
    *(uint4*)(dst)     = *(uint4*)&u[0];
    *(uint4*)(dst + 4) = *(uint4*)&u[4];
}

// ---------- main attention kernel ----------
__global__ __launch_bounds__(256, 5) void l2q_main(
    const float* __restrict__ q,
    const unsigned short* __restrict__ kbf, const unsigned short* __restrict__ vtbf,
    const float* __restrict__ alpha, const float* __restrict__ beta, const float* __restrict__ gamma,
    float* __restrict__ out)
{
    // 32-key tiles. K: 32 rows x 64d bf16 (32 uints/row). V: 64 d-rows x 32 keys (16 uints/row).
    // P per wave: 32 q-rows x 32 keys (16 uints/row). Total LDS = 24576 B -> 5+ blocks/CU.
    __shared__ __align__(16) unsigned Ks[2][1024];
    __shared__ __align__(16) unsigned Vs[2][1024];
    __shared__ __align__(16) unsigned Pu[4][512];

    const int bid  = blockIdx.x;
    // XCD-aware decode: xcd = bid & 7 (dispatch round-robin); pin 12 heads per XCD.
    const int xcd  = bid & 7;
    const int s    = bid >> 3;                 // 0..95
    const int bh   = xcd * 12 + (s % 12);
    const int qt   = s / 12;                   // 0..7
    const int h    = bh % kH;
    const int t    = threadIdx.x;
    const int wave = t >> 6;
    const int lane = t & 63;
    const int quad = lane >> 4;
    const int l15  = lane & 15;

    const float al = alpha[h] * (kScale * kScale);
    const float be = beta[h] * kScale;
    const float ga = gamma[h];

    const float* qp = q + (long)bh * kND;
    const unsigned short* kp = kbf + (long)bh * kND;
    const unsigned short* vp = vtbf + (long)bh * kND;   // [d][n]

    // Q fragments from fp32 (read once): lane holds Q[q=qb*16+l15][d=kc*32+quad*8+j]
    bf16x8 qa[2][2];
#pragma unroll
    for (int qb = 0; qb < 2; ++qb) {
        const int row = qt * 128 + wave * 32 + qb * 16 + l15;
#pragma unroll
        for (int kc = 0; kc < 2; ++kc) {
            const float* src = qp + (long)row * kD + kc * 32 + quad * 8;
            const float4 f0 = *(const float4*)(src);
            const float4 f1 = *(const float4*)(src + 4);
            uint4 u;
            u.x = pack2_rne(f0.x, f0.y);
            u.y = pack2_rne(f0.z, f0.w);
            u.z = pack2_rne(f1.x, f1.y);
            u.w = pack2_rne(f1.z, f1.w);
            qa[qb][kc] = __builtin_bit_cast(bf16x8, u);
        }
    }

    f32x4 oacc[2][4];
#pragma unroll
    for (int qb = 0; qb < 2; ++qb)
#pragma unroll
        for (int db = 0; db < 4; ++db)
            oacc[qb][db] = (f32x4){0.f, 0.f, 0.f, 0.f};
    f32x4 dsv[2] = {(f32x4){0.f,0.f,0.f,0.f}, (f32x4){0.f,0.f,0.f,0.f}};

    // staging: per tile each wave issues 1 K + 1 V gl_lds16 (4KB each across block)
    const int krow = wave * 8 + (lane >> 3);        // 0..31
    const int kgl  = (((lane & 7) ^ (krow & 7))) * 8;
    const int vrow = wave * 16 + (lane >> 2);       // 0..63
    const int vgl  = (((lane & 3) ^ (vrow & 3))) * 8;
    auto stageKV = [&](int buf, int tile) {
        const int k0 = tile * 32;
        gl_lds16(kp + (long)(k0 + krow) * kD + kgl, &Ks[buf][wave * 256]);
        gl_lds16(vp + (long)vrow * kN + k0 + vgl,   &Vs[buf][wave * 256]);
    };

    stageKV(0, 0);
    unsigned* Pw = Pu[wave];
    const int sw3 = l15 & 3, sw7 = l15 & 7;

    for (int tile = 0; tile < kTiles; ++tile) {
        const int buf = tile & 1;
        __syncthreads();
        if (tile + 1 < kTiles) stageKV(buf ^ 1, tile + 1);

        const unsigned* Kb = Ks[buf];
        const unsigned* Vb = Vs[buf];

        // ---- S^T = K Q^T : C[m=key(16-blk kb)][n=q]; lane: 4 keys (quad*4+i), q=l15 ----
        f32x4 st[2][2];
#pragma unroll
        for (int qb = 0; qb < 2; ++qb)
#pragma unroll
            for (int kb = 0; kb < 2; ++kb)
                st[qb][kb] = (f32x4){0.f, 0.f, 0.f, 0.f};
#pragma unroll
        for (int kb = 0; kb < 2; ++kb) {
            const int row = (kb * 16 + l15) * 32;
            bf16x8 kf0 = *(const bf16x8*)&Kb[row + ((quad ^ sw7) << 2)];
            bf16x8 kf1 = *(const bf16x8*)&Kb[row + (((4 + quad) ^ sw7) << 2)];
#pragma unroll
            for (int qb = 0; qb < 2; ++qb) {
                st[qb][kb] = MFMA16(kf0, qa[qb][0], st[qb][kb]);
                st[qb][kb] = MFMA16(kf1, qa[qb][1], st[qb][kb]);
            }
        }

        // ---- poly + ReLU + denom + pack P (bf16 pairs in-lane) ----
#pragma unroll
        for (int qb = 0; qb < 2; ++qb) {
            const int pbase = (qb * 16 + l15) * 16;
#pragma unroll
            for (int kb = 0; kb < 2; ++kb) {
                f32x4 sfr = st[qb][kb];
                f32x4 w = sfr * al + be;
                w = w * sfr + ga;
                w[0] = fmaxf(w[0], 0.f); w[1] = fmaxf(w[1], 0.f);
                w[2] = fmaxf(w[2], 0.f); w[3] = fmaxf(w[3], 0.f);
                dsv[qb] += w;
                uint2 pk2;
                pk2.x = pack2_rhu(w[0], w[1]);
                pk2.y = pack2_rhu(w[2], w[3]);
                // keys kb*16+quad*4+{0..3} -> uint col kb*8+quad*2 -> granule kb*2+(quad>>1), off (quad&1)*2
                const int gr = kb * 2 + (quad >> 1);
                *(uint2*)&Pw[pbase + ((gr ^ sw3) << 2) + (quad & 1) * 2] = pk2;
            }
        }
        __asm__ __volatile__("" ::: "memory");   // order P writes before P reads

        // ---- O += P V : A=P[q][key] (1 frag/qb, K=32), B=Vt rows ----
        bf16x8 pf[2];
        pf[0] = *(const bf16x8*)&Pw[(l15)      * 16 + ((quad ^ sw3) << 2)];
        pf[1] = *(const bf16x8*)&Pw[(16 + l15) * 16 + ((quad ^ sw3) << 2)];
#pragma unroll
        for (int db = 0; db < 4; ++db) {
            bf16x8 vf = *(const bf16x8*)&Vb[(db * 16 + l15) * 16 + ((quad ^ sw3) << 2)];
            oacc[0][db] = MFMA16(pf[0], vf, oacc[0][db]);
            oacc[1][db] = MFMA16(pf[1], vf, oacc[1][db]);
        }
        __asm__ __volatile__("" ::: "memory");   // order P reads before next tile's writes
    }

    // ---- denominator: horizontal + cross-quad reduce (q = l15) ----
    float dr[2];
#pragma unroll
    for (int qb = 0; qb < 2; ++qb) {
        float d = dsv[qb][0] + dsv[qb][1] + dsv[qb][2] + dsv[qb][3];
        d += __shfl_xor(d, 16);
        d += __shfl_xor(d, 32);
        dr[qb] = 1.0f / (d + kEps);
    }

    const long obase = (long)bh * kND;
#pragma unroll
    for (int qb = 0; qb < 2; ++qb)
#pragma unroll
        for (int i = 0; i < 4; ++i) {
            const float rr = __shfl(dr[qb], quad * 4 + i);
            const int row = qt * 128 + wave * 32 + qb * 16 + quad * 4 + i;
#pragma unroll
            for (int db = 0; db < 4; ++db)
                out[obase + (long)row * kD + db * 16 + l15] = oacc[qb][db][i] * rr;
        }
}

// ---------- fallback (fp32 direct, R1 kernel) for small ws ----------
static constexpr int KSU = 36;
static constexpr int VSU = 36;
static constexpr int PSU = 36;

__global__ __launch_bounds__(256, 3) void l2q_attn_fb(
    const float* __restrict__ q, const float* __restrict__ k, const float* __restrict__ v,
    const float* __restrict__ alpha, const float* __restrict__ beta, const float* __restrict__ gamma,
    float* __restrict__ out)
{
    __shared__ __align__(16) unsigned KsU[64 * KSU];
    __shared__ __align__(16) unsigned VtU[64 * VSU];
    __shared__ __align__(16) unsigned PU[128 * PSU];

    const int bid  = blockIdx.x;
    const int bh   = bid >> 3;
    const int qt   = bid & 7;
    const int h    = bh % kH;
    const int t    = threadIdx.x;
    const int wave = t >> 6;
    const int lane = t & 63;
    const int quad = lane >> 4;
    const int l15  = lane & 15;

    const float al = alpha[h], be = beta[h], ga = gamma[h];

    const long base = (long)bh * kN * kD;
    const float* qp = q + base;
    const float* kp = k + base;
    const float* vp = v + base;

    bf16x8 qa[2][2];
#pragma unroll
    for (int rb = 0; rb < 2; ++rb) {
        const int row = qt * 128 + wave * 32 + rb * 16 + l15;
#pragma unroll
        for (int kc = 0; kc < 2; ++kc) {
            const float* src = qp + (long)row * kD + kc * 32 + quad * 8;
            const float4 f0 = *(const float4*)(src);
            const float4 f1 = *(const float4*)(src + 4);
            uint4 u;
            u.x = pack2_rne(f0.x, f0.y);
            u.y = pack2_rne(f0.z, f0.w);
            u.z = pack2_rne(f1.x, f1.y);
            u.w = pack2_rne(f1.z, f1.w);
            qa[rb][kc] = __builtin_bit_cast(bf16x8, u);
        }
    }

    f32x4 oacc[2][4];
#pragma unroll
    for (int rb = 0; rb < 2; ++rb)
#pragma unroll
        for (int db = 0; db < 4; ++db)
            oacc[rb][db] = (f32x4){0.f, 0.f, 0.f, 0.f};

    float dsum[2][4] = {{0.f, 0.f, 0.f, 0.f}, {0.f, 0.f, 0.f, 0.f}};
    unsigned* Pw = &PU[wave * 32 * PSU];

    for (int tile = 0; tile < 16; ++tile) {
        __syncthreads();
        const int k0 = tile * 64;
#pragma unroll
        for (int r = 0; r < 4; ++r) {
            const int f4 = t + 256 * r;
            const int n = f4 >> 4, d4 = f4 & 15;
            const float4 kg = *(const float4*)(kp + (long)(k0 + n) * kD + 4 * d4);
            uint2 pk;
            pk.x = pack2_rne(kg.x, kg.y);
            pk.y = pack2_rne(kg.z, kg.w);
            *(uint2*)&KsU[n * KSU + 2 * d4] = pk;
        }
#pragma unroll
        for (int r = 0; r < 2; ++r) {
            const int u = t + 256 * r;
            const int key2 = u & 31, d4 = u >> 5;
            const float* s0 = vp + (long)(k0 + 2 * key2) * kD + 4 * d4;
            const float4 va = *(const float4*)(s0);
            const float4 vb = *(const float4*)(s0 + kD);
            VtU[(4 * d4 + 0) * VSU + key2] = pack2_rne(va.x, vb.x);
            VtU[(4 * d4 + 1) * VSU + key2] = pack2_rne(va.y, vb.y);
            VtU[(4 * d4 + 2) * VSU + key2] = pack2_rne(va.z, vb.z);
            VtU[(4 * d4 + 3) * VSU + key2] = pack2_rne(va.w, vb.w);
        }
        __syncthreads();

        f32x4 s[2][4];
#pragma unroll
        for (int rb = 0; rb < 2; ++rb)
#pragma unroll
            for (int nb = 0; nb < 4; ++nb)
                s[rb][nb] = (f32x4){0.f, 0.f, 0.f, 0.f};
#pragma unroll
        for (int nb = 0; nb < 4; ++nb) {
            bf16x8 kb0 = *(const bf16x8*)&KsU[(nb * 16 + l15) * KSU + 4 * quad];
            bf16x8 kb1 = *(const bf16x8*)&KsU[(nb * 16 + l15) * KSU + 16 + 4 * quad];
#pragma unroll
            for (int rb = 0; rb < 2; ++rb) {
                s[rb][nb] = MFMA16(qa[rb][0], kb0, s[rb][nb]);
                s[rb][nb] = MFMA16(qa[rb][1], kb1, s[rb][nb]);
            }
        }

        const bool ev = (lane & 1) == 0;
#pragma unroll
        for (int rb = 0; rb < 2; ++rb) {
#pragma unroll
            for (int nb = 0; nb < 4; ++nb) {
                float w0, w1, w2, w3;
                {
                    float l0 = s[rb][nb][0] * kScale;
                    float l1 = s[rb][nb][1] * kScale;
                    float l2 = s[rb][nb][2] * kScale;
                    float l3 = s[rb][nb][3] * kScale;
                    w0 = fmaxf(fmaf(fmaf(al, l0, be), l0, ga), 0.f);
                    w1 = fmaxf(fmaf(fmaf(al, l1, be), l1, ga), 0.f);
                    w2 = fmaxf(fmaf(fmaf(al, l2, be), l2, ga), 0.f);
                    w3 = fmaxf(fmaf(fmaf(al, l3, be), l3, ga), 0.f);
                }
                dsum[rb][0] += w0; dsum[rb][1] += w1;
                dsum[rb][2] += w2; dsum[rb][3] += w3;

                const float o0 = __shfl_xor(w0, 1);
                const float o1 = __shfl_xor(w1, 1);
                const float o2 = __shfl_xor(w2, 1);
                const float o3 = __shfl_xor(w3, 1);
                const unsigned pa = ev ? pack2_rne(w0, o0) : pack2_rne(o2, w2);
                const unsigned pb = ev ? pack2_rne(w1, o1) : pack2_rne(o3, w3);
                const int r0 = ev ? 0 : 2;
                const int cu = (16 * nb + (l15 & ~1)) >> 1;
                const int rowb = rb * 16 + quad * 4 + r0;
                Pw[rowb * PSU + cu] = pa;
                Pw[(rowb + 1) * PSU + cu] = pb;
            }
        }

        bf16x8 pf[2][2];
#pragma unroll
        for (int rb = 0; rb < 2; ++rb)
#pragma unroll
            for (int kc = 0; kc < 2; ++kc)
                pf[rb][kc] = *(const bf16x8*)&Pw[(rb * 16 + l15) * PSU + 16 * kc + 4 * quad];
#pragma unroll
        for (int db = 0; db < 4; ++db) {
            bf16x8 vf0 = *(const bf16x8*)&VtU[(db * 16 + l15) * VSU + 4 * quad];
            bf16x8 vf1 = *(const bf16x8*)&VtU[(db * 16 + l15) * VSU + 16 + 4 * quad];
#pragma unroll
            for (int rb = 0; rb < 2; ++rb) {
                oacc[rb][db] = MFMA16(pf[rb][0], vf0, oacc[rb][db]);
                oacc[rb][db] = MFMA16(pf[rb][1], vf1, oacc[rb][db]);
            }
        }
    }

#pragma unroll
    for (int rb = 0; rb < 2; ++rb)
#pragma unroll
        for (int i = 0; i < 4; ++i) {
            float d = dsum[rb][i];
            d += __shfl_xor(d, 1);
            d += __shfl_xor(d, 2);
            d += __shfl_xor(d, 4);
            d += __shfl_xor(d, 8);
            dsum[rb][i] = 1.0f / (d + kEps);
        }

#pragma unroll
    for (int rb = 0; rb < 2; ++rb)
#pragma unroll
        for (int db = 0; db < 4; ++db)
#pragma unroll
            for (int i = 0; i < 4; ++i) {
                const int row = qt * 128 + wave * 32 + rb * 16 + quad * 4 + i;
                out[base + (long)row * kD + db * 16 + l15] = oacc[rb][db][i] * dsum[rb][i];
            }
}

extern "C" void kernel_launch(void* const* d_in, const int* in_sizes, int n_in,
                              void* d_out, int out_size, void* d_ws, size_t ws_size,
                              hipStream_t stream) {
    const float* q     = (const float*)d_in[0];
    const float* k     = (const float*)d_in[1];
    const float* v     = (const float*)d_in[2];
    const float* alpha = (const float*)d_in[3];
    const float* beta  = (const float*)d_in[4];
    const float* gamma = (const float*)d_in[5];
    float* out = (float*)d_out;

    if (ws_size < (size_t)kWsNeeded) {
        l2q_attn_fb<<<dim3(768), dim3(256), 0, stream>>>(q, k, v, alpha, beta, gamma, out);
        return;
    }

    unsigned* kbf = (unsigned*)d_ws;
    unsigned* vtb = kbf + kTensorElems / 2;

    prep<<<dim3(1536), dim3(256), 0, stream>>>(k, v, kbf, vtb);
    l2q_main<<<dim3(768), dim3(256), 0, stream>>>(
        q, (const unsigned short*)kbf, (const unsigned short*)vtb,
        alpha, beta, gamma, out);
}